// Round 9
// baseline (319.828 us; speedup 1.0000x reference)
//
#include <hip/hip_runtime.h>

// ---- problem constants ----
constexpr int B  = 4;
constexpr int T  = 2048;
constexpr int D  = 1024;
constexpr int H  = 16;
constexpr int DH = 64;
constexpr int BT = B * T;

// Inputs f32, output f32.  Internal bf16 MFMA, f32 accumulate.
// d_out scratch: [0..6MB) WT (3xDxD bf16 transposed weights, dead after gemm);
// then attn overwrites d_out with f32, ln runs in place.
// d_ws holds Qp/Kp/Vt (48 MB bf16).  Qp prescaled by 0.125*log2(e).

typedef __attribute__((ext_vector_type(8))) short bf16x8;
typedef __attribute__((ext_vector_type(4))) float f32x4;
typedef __attribute__((ext_vector_type(4))) unsigned short u16x4;
typedef __attribute__((ext_vector_type(4))) unsigned int u32x4;

static __device__ __forceinline__ unsigned short f2bf(float f) {
    unsigned u = __builtin_bit_cast(unsigned, f);
    unsigned r = (u + 0x7fffu + ((u >> 16) & 1u)) >> 16;  // RNE
    return (unsigned short)r;
}

// packed f32x2 -> bf16x2 (RNE), gfx950 has no builtin (m240) -> inline asm
static __device__ __forceinline__ unsigned cvt_pk_bf16(float lo, float hi) {
    unsigned r;
    asm("v_cvt_pk_bf16_f32 %0, %1, %2" : "=v"(r) : "v"(lo), "v"(hi));
    return r;
}

// quad-granular cross-lane swaps (gfx950).
static __device__ __forceinline__ void pl32swap(unsigned &a, unsigned &b) {
    asm volatile("v_permlane32_swap_b32 %0, %1" : "+v"(a), "+v"(b));
}
static __device__ __forceinline__ void pl16swap(unsigned &a, unsigned &b) {
    asm volatile("v_permlane16_swap_b32 %0, %1" : "+v"(a), "+v"(b));
}

// global -> LDS direct 16B stage (gfx950).
static __device__ __forceinline__ void stage16(const unsigned short* g, unsigned short* l) {
    __builtin_amdgcn_global_load_lds(
        (const __attribute__((address_space(1))) unsigned int*)g,
        (__attribute__((address_space(3))) unsigned int*)l, 16, 0, 0);
}

// counted waits + raw barrier helpers (T4): never drain vmcnt to 0 in-loop.
static __device__ __forceinline__ void wait_vm12_lgkm0() {
    asm volatile("s_waitcnt vmcnt(12) lgkmcnt(0)" ::: "memory");
}
static __device__ __forceinline__ void wait_vm4() {
    asm volatile("s_waitcnt vmcnt(4)" ::: "memory");
}
static __device__ __forceinline__ void wait_lgkm0() {
    asm volatile("s_waitcnt lgkmcnt(0)" ::: "memory");
}
static __device__ __forceinline__ void wait_all() {
    asm volatile("s_waitcnt vmcnt(0) lgkmcnt(0)" ::: "memory");
}
static __device__ __forceinline__ void barrier_raw() {
    __builtin_amdgcn_s_barrier();
    __builtin_amdgcn_sched_barrier(0);
}

// ---------------------------------------------------------------------------
// Stage 0: transpose+convert weights -> bf16 (N x K) row-major (into d_out).
// ---------------------------------------------------------------------------
__global__ __launch_bounds__(256) void transpose_w(
    const float* __restrict__ Wq,
    const float* __restrict__ Wk,
    const float* __restrict__ Wv,
    unsigned short* __restrict__ WT) {
    __shared__ unsigned short tile[32][33];
    const float* src = (blockIdx.y == 0) ? Wq : (blockIdx.y == 1) ? Wk : Wv;
    unsigned short* dst = WT + (size_t)blockIdx.y * D * D;
    int tx = blockIdx.x % (D / 32);
    int ty = blockIdx.x / (D / 32);
    int c  = threadIdx.x & 31;
    int r0 = threadIdx.x >> 5;
#pragma unroll
    for (int i = 0; i < 4; i++) {
        int r = r0 + i * 8;
        tile[r][c] = f2bf(src[(size_t)(ty * 32 + r) * D + tx * 32 + c]);
    }
    __syncthreads();
#pragma unroll
    for (int i = 0; i < 4; i++) {
        int r = r0 + i * 8;
        dst[(size_t)(tx * 32 + r) * D + ty * 32 + c] = tile[c][r];
    }
}

// ---------------------------------------------------------------------------
// Stage 1: FUSED projection GEMM with counted-vmcnt pipeline (T4):
//   per iter: issue A-loads(kt+1) then B-stages(kt+1) [12 vmem, NEWEST];
//   top-of-iter wait vmcnt(12) retires only B-stages(kt) — they had a full
//   iteration in flight, zero stall; prefetches CROSS the raw s_barrier.
//   Post-MFMA: lgkm-only barrier, then vmcnt(4) (A done, B still flying),
//   cvt + write-late into single-buffered Als.  Last iteration peeled
//   (full drain).  All waits are asm+memory-fence; barriers are raw.
// ---------------------------------------------------------------------------
__global__ __launch_bounds__(256, 3) void qkv_gemm_fused(
    const float* __restrict__ Xq,
    const float* __restrict__ Xk,
    const float* __restrict__ Xv,
    const unsigned short* __restrict__ WTall,  // 3 x [D][D] bf16 (n-major)
    const float* __restrict__ bq,
    const float* __restrict__ bk,
    const float* __restrict__ bv,
    unsigned short* __restrict__ Qp,
    unsigned short* __restrict__ Kp,
    unsigned short* __restrict__ Vt) {
    __shared__ __align__(16) unsigned short Als[128 * 64];
    __shared__ __align__(16) unsigned short Bls[2][128 * 64];

    const int which = blockIdx.y;
    const float* X = (which == 0) ? Xq : (which == 1) ? Xk : Xv;
    const unsigned short* Wt = WTall + (size_t)which * D * D;
    const float* bias = (which == 0) ? bq : (which == 1) ? bk : bv;

    int bx = blockIdx.x;
    // bijective XCD swizzle: 512 = 8*64; XCD x owns mblks [8x, 8x+8)
    int sb   = (bx & 7) * 64 + (bx >> 3);
    int nblk = sb & 7;
    int mblk = sb >> 3;
    int tid  = threadIdx.x;
    int wave = tid >> 6, lane = tid & 63;
    int lane15 = lane & 15, quad = lane >> 4;
    int wm = (wave >> 1) * 64;
    int wn = (wave & 1) * 64;

    const size_t m0 = (size_t)mblk * 128;
    const size_t n0 = (size_t)nblk * 128;

    // per-thread staging geometry (fixed): chunk ids {j*256+tid}
    int srow[4], ssg[4];
#pragma unroll
    for (int j = 0; j < 4; j++) {
        int id  = j * 256 + tid;
        srow[j] = id >> 3;
        ssg[j]  = (id & 7) ^ (srow[j] & 7);
    }

    f32x4 acc[4][4] = {};
    f32x4 xa[4][2];

    constexpr int NT = D / 64;

    // ---- prologue: A-loads(0) FIRST, then B-stage(0) (B stays in flight
    // through the cvt's implicit vmcnt wait), cvt+write A(0) ----
#pragma unroll
    for (int j = 0; j < 4; j++) {
        const float* src = X + (m0 + srow[j]) * D + ssg[j] * 8;
        xa[j][0] = *(const f32x4*)(src);
        xa[j][1] = *(const f32x4*)(src + 4);
    }
#pragma unroll
    for (int j = 0; j < 4; j++)
        stage16(Wt + (n0 + srow[j]) * D + ssg[j] * 8,
                Bls[0] + (size_t)(j * 256 + wave * 64) * 8);
#pragma unroll
    for (int j = 0; j < 4; j++) {
        u32x4 w;
        w[0] = cvt_pk_bf16(xa[j][0][0], xa[j][0][1]);
        w[1] = cvt_pk_bf16(xa[j][0][2], xa[j][0][3]);
        w[2] = cvt_pk_bf16(xa[j][1][0], xa[j][1][1]);
        w[3] = cvt_pk_bf16(xa[j][1][2], xa[j][1][3]);
        *(bf16x8*)(Als + (size_t)(j * 256 + tid) * 8) = __builtin_bit_cast(bf16x8, w);
    }

    int c = 0;
    for (int kt = 0; kt < NT - 1; kt++) {
        int kn = (kt + 1) * 64;
        // 12 new vmem ops: A-loads (8, older) then B-stages (4, newest)
#pragma unroll
        for (int j = 0; j < 4; j++) {
            const float* src = X + (m0 + srow[j]) * D + kn + ssg[j] * 8;
            xa[j][0] = *(const f32x4*)(src);
            xa[j][1] = *(const f32x4*)(src + 4);
        }
#pragma unroll
        for (int j = 0; j < 4; j++)
            stage16(Wt + (n0 + srow[j]) * D + kn + ssg[j] * 8,
                    Bls[c ^ 1] + (size_t)(j * 256 + wave * 64) * 8);

        // retire B-stages(kt) (a full iteration old) + own A ds_writes;
        // the 12 just-issued ops stay in flight across the barrier.
        wait_vm12_lgkm0();
        barrier_raw();

        // fragments for step kt
        bf16x8 af[2][4], bfr[2][4];
#pragma unroll
        for (int h = 0; h < 2; h++) {
#pragma unroll
            for (int i = 0; i < 4; i++) {
                int rowa = wm + i * 16 + lane15;
                int ga   = (h * 4 + quad) ^ (rowa & 7);
                af[h][i] = *(const bf16x8*)(Als + (size_t)rowa * 64 + ga * 8);
                int rowb = wn + i * 16 + lane15;
                int gb   = (h * 4 + quad) ^ (rowb & 7);
                bfr[h][i] = *(const bf16x8*)(Bls[c] + (size_t)rowb * 64 + gb * 8);
            }
        }
#pragma unroll
        for (int h = 0; h < 2; h++)
#pragma unroll
            for (int mi = 0; mi < 4; mi++)
#pragma unroll
                for (int nf = 0; nf < 4; nf++)
                    acc[mi][nf] = __builtin_amdgcn_mfma_f32_16x16x32_bf16(
                        af[h][mi], bfr[h][nf], acc[mi][nf], 0, 0, 0);

        // all waves done reading Als (their frag ds_reads are serviced before
        // their MFMAs); exec-sync only — NO vmem drain here.
        wait_lgkm0();
        barrier_raw();

        // A-loads(kt+1) done (vmcnt(4) leaves the 4 B-stages flying); cvt +
        // write-late into Als.
        wait_vm4();
#pragma unroll
        for (int j = 0; j < 4; j++) {
            u32x4 w;
            w[0] = cvt_pk_bf16(xa[j][0][0], xa[j][0][1]);
            w[1] = cvt_pk_bf16(xa[j][0][2], xa[j][0][3]);
            w[2] = cvt_pk_bf16(xa[j][1][0], xa[j][1][1]);
            w[3] = cvt_pk_bf16(xa[j][1][2], xa[j][1][3]);
            *(bf16x8*)(Als + (size_t)(j * 256 + tid) * 8) = __builtin_bit_cast(bf16x8, w);
        }
        c ^= 1;
    }

    // peeled last iteration: full drain, then compute.
    wait_all();
    barrier_raw();
    {
        bf16x8 af[2][4], bfr[2][4];
#pragma unroll
        for (int h = 0; h < 2; h++) {
#pragma unroll
            for (int i = 0; i < 4; i++) {
                int rowa = wm + i * 16 + lane15;
                int ga   = (h * 4 + quad) ^ (rowa & 7);
                af[h][i] = *(const bf16x8*)(Als + (size_t)rowa * 64 + ga * 8);
                int rowb = wn + i * 16 + lane15;
                int gb   = (h * 4 + quad) ^ (rowb & 7);
                bfr[h][i] = *(const bf16x8*)(Bls[c] + (size_t)rowb * 64 + gb * 8);
            }
        }
#pragma unroll
        for (int h = 0; h < 2; h++)
#pragma unroll
            for (int mi = 0; mi < 4; mi++)
#pragma unroll
                for (int nf = 0; nf < 4; nf++)
                    acc[mi][nf] = __builtin_amdgcn_mfma_f32_16x16x32_bf16(
                        af[h][mi], bfr[h][nf], acc[mi][nf], 0, 0, 0);
    }

    const float scl = (which == 0) ? 0.18033688011112042f : 1.0f;
    if (which == 2) {
        // V: pack 4 t-consecutive outputs -> one 8B store
#pragma unroll
        for (int nf = 0; nf < 4; nf++) {
            int n = nblk * 128 + wn + nf * 16 + lane15;
            float bn = bias[n];
            int h = n >> 6, d = n & 63;
#pragma unroll
            for (int mi = 0; mi < 4; mi++) {
                int t0 = mblk * 128 + wm + mi * 16 + quad * 4;
                int b_ = t0 >> 11;
                int tt = t0 & (T - 1);
                u16x4 o;
#pragma unroll
                for (int r = 0; r < 4; r++) o[r] = f2bf(acc[mi][nf][r] + bn);
                *(u16x4*)(Vt + (size_t)((b_ * H + h) * DH + d) * T + tt) = o;
            }
        }
    } else {
        unsigned short* P = (which == 0) ? Qp : Kp;
#pragma unroll
        for (int nf = 0; nf < 4; nf++) {
            int n = nblk * 128 + wn + nf * 16 + lane15;
            float bn = bias[n];
            int h = n >> 6, d = n & 63;
#pragma unroll
            for (int mi = 0; mi < 4; mi++) {
#pragma unroll
                for (int r = 0; r < 4; r++) {
                    int m  = mblk * 128 + wm + mi * 16 + quad * 4 + r;
                    int b_ = m >> 11;
                    int t  = m & (T - 1);
                    P[(size_t)((b_ * H + h) * T + t) * DH + d] =
                        f2bf((acc[mi][nf][r] + bn) * scl);
                }
            }
        }
    }
}

// ---------------------------------------------------------------------------
// Stage 2: flash attention (UNCHANGED — clean attribution).
// ---------------------------------------------------------------------------
__global__ __launch_bounds__(256, 2) void attn_kernel(
    const unsigned short* __restrict__ Qp,
    const unsigned short* __restrict__ Kp,
    const unsigned short* __restrict__ Vt,
    float* __restrict__ AO) {
    __shared__ __align__(16) unsigned short Kls[2][64 * 64];
    __shared__ __align__(16) unsigned short Vls[2][64 * 64];

    constexpr int NT = T / 64;

    int bx = blockIdx.x;
    // bijective XCD swizzle: grid=1024=8*128; XCD x gets bh in [8x, 8x+8)
    int sb = (bx & 7) * 128 + (bx >> 3);
    int qt = sb & 15;           // 16 q-tiles of 128 rows
    int bh = sb >> 4;

    int tid  = threadIdx.x;
    int wave = tid >> 6, lane = tid & 63;
    int lane15 = lane & 15, quad = lane >> 4;

    const unsigned short* Qb = Qp + (size_t)bh * T * DH;
    const unsigned short* Kb = Kp + (size_t)bh * T * DH;
    const unsigned short* Vb = Vt + (size_t)bh * DH * T;

    int qbase = qt * 128 + wave * 32;
    bf16x8 qa[2][2];
#pragma unroll
    for (int mi = 0; mi < 2; mi++)
#pragma unroll
        for (int hh = 0; hh < 2; hh++)
            qa[mi][hh] = *(const bf16x8*)(
                Qb + (size_t)(qbase + mi * 16 + lane15) * DH + hh * 32 + quad * 8);

    float ps[2] = {0.f, 0.f};
    f32x4 O[2][4] = {};

    // prologue: stage tile 0 into buf 0
#pragma unroll
    for (int i = 0; i < 2; i++) {
        int gl = i * 256 + tid;
        int row = gl >> 3, c = gl & 7;
        int sg = c ^ (row & 7);
        stage16(Kb + (size_t)row * DH + sg * 8,
                &Kls[0][(size_t)(i * 256 + wave * 64) * 8]);
        stage16(Vb + (size_t)row * T + sg * 8,
                &Vls[0][(size_t)(i * 256 + wave * 64) * 8]);
    }
    __syncthreads();

    int cur = 0;
    for (int kt = 0; kt < NT; kt++) {
        if (kt + 1 < NT) {
            int nkb = (kt + 1) * 64;
#pragma unroll
            for (int i = 0; i < 2; i++) {
                int gl = i * 256 + tid;
                int row = gl >> 3, c = gl & 7;
                int sg = c ^ (row & 7);
                stage16(Kb + (size_t)(nkb + row) * DH + sg * 8,
                        &Kls[cur ^ 1][(size_t)(i * 256 + wave * 64) * 8]);
                stage16(Vb + (size_t)row * T + nkb + sg * 8,
                        &Vls[cur ^ 1][(size_t)(i * 256 + wave * 64) * 8]);
            }
        }

        bf16x8 kf[4][2];
#pragma unroll
        for (int nf = 0; nf < 4; nf++) {
            int r = nf * 16 + lane15;
#pragma unroll
            for (int hh = 0; hh < 2; hh++) {
                int ch = (hh * 4 + quad) ^ (r & 7);
                kf[nf][hh] = *(const bf16x8*)(&Kls[cur][(size_t)r * 64 + ch * 8]);
            }
        }

        f32x4 st[4][2] = {};
        __builtin_amdgcn_s_setprio(1);
#pragma unroll
        for (int nf = 0; nf < 4; nf++)
#pragma unroll
            for (int mi = 0; mi < 2; mi++) {
                st[nf][mi] = __builtin_amdgcn_mfma_f32_16x16x32_bf16(
                    kf[nf][0], qa[mi][0], st[nf][mi], 0, 0, 0);
                st[nf][mi] = __builtin_amdgcn_mfma_f32_16x16x32_bf16(
                    kf[nf][1], qa[mi][1], st[nf][mi], 0, 0, 0);
            }
        __builtin_amdgcn_s_setprio(0);

        unsigned e[4][2][2];
#pragma unroll
        for (int nf = 0; nf < 4; nf++)
#pragma unroll
            for (int mi = 0; mi < 2; mi++) {
                f32x4 p;
#pragma unroll
                for (int r = 0; r < 4; r++) {
                    p[r] = __builtin_amdgcn_exp2f(st[nf][mi][r]);
                    ps[mi] += p[r];
                }
                e[nf][mi][0] = cvt_pk_bf16(p[0], p[1]);
                e[nf][mi][1] = cvt_pk_bf16(p[2], p[3]);
            }

        bf16x8 vf[4][2];
#pragma unroll
        for (int nf = 0; nf < 4; nf++) {
            int r = nf * 16 + lane15;
#pragma unroll
            for (int hh = 0; hh < 2; hh++) {
                int ch = (hh * 4 + quad) ^ (r & 7);
                vf[nf][hh] = *(const bf16x8*)(&Vls[cur][(size_t)r * 64 + ch * 8]);
            }
        }

        __builtin_amdgcn_s_setprio(1);
#pragma unroll
        for (int mi = 0; mi < 2; mi++) {
#pragma unroll
            for (int ks = 0; ks < 2; ks++) {
                unsigned a0 = e[2 * ks][mi][0], b0 = e[2 * ks + 1][mi][0];
                pl32swap(a0, b0);
                pl16swap(a0, b0);
                unsigned a1 = e[2 * ks][mi][1], b1 = e[2 * ks + 1][mi][1];
                pl32swap(a1, b1);
                pl16swap(a1, b1);
                u32x4 w;
                w[0] = a0; w[1] = a1; w[2] = b0; w[3] = b1;
                bf16x8 pa = __builtin_bit_cast(bf16x8, w);
#pragma unroll
                for (int nf = 0; nf < 4; nf++)
                    O[mi][nf] = __builtin_amdgcn_mfma_f32_16x16x32_bf16(
                        pa, vf[nf][ks], O[mi][nf], 0, 0, 0);
            }
        }
        __builtin_amdgcn_s_setprio(0);

        __syncthreads();
        cur ^= 1;
    }

    float dinv[2][4];
#pragma unroll
    for (int mi = 0; mi < 2; mi++) {
        ps[mi] += __shfl_xor(ps[mi], 16);
        ps[mi] += __shfl_xor(ps[mi], 32);
        float iv = 1.0f / ps[mi];
#pragma unroll
        for (int r = 0; r < 4; r++)
            dinv[mi][r] = __shfl(iv, (lane & 48) + ((lane >> 4) & 3) * 4 + r);
    }

    int hd = bh & 15;
    int b_ = bh >> 4;
#pragma unroll
    for (int mi = 0; mi < 2; mi++) {
#pragma unroll
        for (int r = 0; r < 4; r++) {
            int t = qbase + mi * 16 + quad * 4 + r;
            float* dst = AO + (size_t)(b_ * T + t) * D + hd * DH;
#pragma unroll
            for (int nf = 0; nf < 4; nf++) {
                dst[nf * 16 + lane15] = O[mi][nf][r] * dinv[mi][r];
            }
        }
    }
}

// ---------------------------------------------------------------------------
// Stage 3: residual + LayerNorm, in place on f32 d_out.  f32x4 vectorized.
// ---------------------------------------------------------------------------
__global__ __launch_bounds__(256) void ln_kernel(
    float* io,
    const float* __restrict__ qin,
    const float* __restrict__ gamma,
    const float* __restrict__ beta) {
    int row = blockIdx.x;
    int tid = threadIdx.x;
    size_t base = (size_t)row * D + tid * 4;
    f32x4 xo = *(const f32x4*)(io + base);
    f32x4 xq = *(const f32x4*)(qin + base);
    f32x4 x;
    float sum = 0.f, ss = 0.f;
#pragma unroll
    for (int i = 0; i < 4; i++) {
        x[i] = xo[i] + xq[i];
        sum += x[i];
        ss += x[i] * x[i];
    }
#pragma unroll
    for (int off = 32; off >= 1; off >>= 1) {
        sum += __shfl_xor(sum, off);
        ss  += __shfl_xor(ss, off);
    }
    __shared__ float s1[4], s2[4];
    int wave = tid >> 6, lane = tid & 63;
    if (lane == 0) { s1[wave] = sum; s2[wave] = ss; }
    __syncthreads();
    sum = s1[0] + s1[1] + s1[2] + s1[3];
    ss  = s2[0] + s2[1] + s2[2] + s2[3];
    float mean = sum * (1.0f / D);
    float var  = (ss - sum * mean) * (1.0f / (D - 1));
    var = fmaxf(var, 0.0f);
    float inv = 1.0f / (sqrtf(var) + 1e-8f);
    f32x4 g = *(const f32x4*)(gamma + tid * 4);
    f32x4 bb = *(const f32x4*)(beta + tid * 4);
    f32x4 o;
#pragma unroll
    for (int i = 0; i < 4; i++) o[i] = g[i] * (x[i] - mean) * inv + bb[i];
    *(f32x4*)(io + base) = o;
}

// ---------------------------------------------------------------------------
extern "C" void kernel_launch(void* const* d_in, const int* in_sizes, int n_in,
                              void* d_out, int out_size, void* d_ws, size_t ws_size,
                              hipStream_t stream) {
    (void)in_sizes; (void)n_in; (void)out_size; (void)ws_size;
    const float* xin[3] = {(const float*)d_in[0], (const float*)d_in[1], (const float*)d_in[2]};
    const float* Wq  = (const float*)d_in[3];
    const float* bq  = (const float*)d_in[4];
    const float* Wk  = (const float*)d_in[5];
    const float* bk  = (const float*)d_in[6];
    const float* Wv  = (const float*)d_in[7];
    const float* bv  = (const float*)d_in[8];
    const float* gam = (const float*)d_in[9];
    const float* bet = (const float*)d_in[10];
    float* out = (float*)d_out;

    unsigned short* ws = (unsigned short*)d_ws;
    unsigned short* Qp = ws;
    unsigned short* Kp = Qp + (size_t)BT * D;
    unsigned short* Vt = Kp + (size_t)BT * D;
    unsigned short* WT = (unsigned short*)d_out;   // 3*D*D bf16 (6 MB), dead after gemm

    transpose_w<<<dim3((D / 32) * (D / 32), 3), 256, 0, stream>>>(Wq, Wk, Wv, WT);
    qkv_gemm_fused<<<dim3((BT / 128) * (D / 128), 3), 256, 0, stream>>>(
        xin[0], xin[1], xin[2], WT, bq, bk, bv, Qp, Kp, Vt);
    attn_kernel<<<dim3(B * H * (T / 128)), 256, 0, stream>>>(Qp, Kp, Vt, out);
    ln_kernel<<<dim3(BT), 256, 0, stream>>>(out, xin[0], gam, bet);
}

// Round 10
// 311.193 us; speedup vs baseline: 1.0277x; 1.0277x over previous
//
#include <hip/hip_runtime.h>

// ---- problem constants ----
constexpr int B  = 4;
constexpr int T  = 2048;
constexpr int D  = 1024;
constexpr int H  = 16;
constexpr int DH = 64;
constexpr int BT = B * T;

// Inputs f32, output f32.  Internal bf16 MFMA, f32 accumulate.
// d_out scratch: [0..6MB) WT (3xDxD bf16 transposed weights, dead after gemm);
// then attn overwrites d_out with f32, ln runs in place.
// d_ws holds Qp/Kp/Vt (48 MB bf16).  Qp prescaled by 0.125*log2(e).

typedef __attribute__((ext_vector_type(8))) short bf16x8;
typedef __attribute__((ext_vector_type(4))) float f32x4;
typedef __attribute__((ext_vector_type(4))) unsigned short u16x4;
typedef __attribute__((ext_vector_type(4))) unsigned int u32x4;

static __device__ __forceinline__ unsigned short f2bf(float f) {
    unsigned u = __builtin_bit_cast(unsigned, f);
    unsigned r = (u + 0x7fffu + ((u >> 16) & 1u)) >> 16;  // RNE
    return (unsigned short)r;
}

// packed f32x2 -> bf16x2 (RNE), gfx950 has no builtin (m240) -> inline asm
static __device__ __forceinline__ unsigned cvt_pk_bf16(float lo, float hi) {
    unsigned r;
    asm("v_cvt_pk_bf16_f32 %0, %1, %2" : "=v"(r) : "v"(lo), "v"(hi));
    return r;
}

// quad-granular cross-lane swaps (gfx950).
static __device__ __forceinline__ void pl32swap(unsigned &a, unsigned &b) {
    asm volatile("v_permlane32_swap_b32 %0, %1" : "+v"(a), "+v"(b));
}
static __device__ __forceinline__ void pl16swap(unsigned &a, unsigned &b) {
    asm volatile("v_permlane16_swap_b32 %0, %1" : "+v"(a), "+v"(b));
}

// global -> LDS direct 16B stage (gfx950).
static __device__ __forceinline__ void stage16(const unsigned short* g, unsigned short* l) {
    __builtin_amdgcn_global_load_lds(
        (const __attribute__((address_space(1))) unsigned int*)g,
        (__attribute__((address_space(3))) unsigned int*)l, 16, 0, 0);
}

// ---------------------------------------------------------------------------
// Stage 0: transpose+convert weights -> bf16 (N x K) row-major (into d_out).
// ---------------------------------------------------------------------------
__global__ __launch_bounds__(256) void transpose_w(
    const float* __restrict__ Wq,
    const float* __restrict__ Wk,
    const float* __restrict__ Wv,
    unsigned short* __restrict__ WT) {
    __shared__ unsigned short tile[32][33];
    const float* src = (blockIdx.y == 0) ? Wq : (blockIdx.y == 1) ? Wk : Wv;
    unsigned short* dst = WT + (size_t)blockIdx.y * D * D;
    int tx = blockIdx.x % (D / 32);
    int ty = blockIdx.x / (D / 32);
    int c  = threadIdx.x & 31;
    int r0 = threadIdx.x >> 5;
#pragma unroll
    for (int i = 0; i < 4; i++) {
        int r = r0 + i * 8;
        tile[r][c] = f2bf(src[(size_t)(ty * 32 + r) * D + tx * 32 + c]);
    }
    __syncthreads();
#pragma unroll
    for (int i = 0; i < 4; i++) {
        int r = r0 + i * 8;
        dst[(size_t)(tx * 32 + r) * D + ty * 32 + c] = tile[c][r];
    }
}

// ---------------------------------------------------------------------------
// Stage 1: FUSED projection GEMM — round-8 structure RESTORED (best measured
// 106 us; counted-vmcnt variant was neutral-negative, T4 is null on 2-phase).
//   * B double-buffered via global_load_lds, staged at top of step kt for kt+1.
//   * A (f32 X) register-prefetched one step ahead; cvt+write-late after the
//     post-MFMA barrier.
// ---------------------------------------------------------------------------
__global__ __launch_bounds__(256, 3) void qkv_gemm_fused(
    const float* __restrict__ Xq,
    const float* __restrict__ Xk,
    const float* __restrict__ Xv,
    const unsigned short* __restrict__ WTall,  // 3 x [D][D] bf16 (n-major)
    const float* __restrict__ bq,
    const float* __restrict__ bk,
    const float* __restrict__ bv,
    unsigned short* __restrict__ Qp,
    unsigned short* __restrict__ Kp,
    unsigned short* __restrict__ Vt) {
    __shared__ __align__(16) unsigned short Als[128 * 64];
    __shared__ __align__(16) unsigned short Bls[2][128 * 64];

    const int which = blockIdx.y;
    const float* X = (which == 0) ? Xq : (which == 1) ? Xk : Xv;
    const unsigned short* Wt = WTall + (size_t)which * D * D;
    const float* bias = (which == 0) ? bq : (which == 1) ? bk : bv;

    int bx = blockIdx.x;
    // bijective XCD swizzle: 512 = 8*64; XCD x owns mblks [8x, 8x+8)
    int sb   = (bx & 7) * 64 + (bx >> 3);
    int nblk = sb & 7;
    int mblk = sb >> 3;
    int tid  = threadIdx.x;
    int wave = tid >> 6, lane = tid & 63;
    int lane15 = lane & 15, quad = lane >> 4;
    int wm = (wave >> 1) * 64;
    int wn = (wave & 1) * 64;

    const size_t m0 = (size_t)mblk * 128;
    const size_t n0 = (size_t)nblk * 128;

    // per-thread staging geometry (fixed): chunk ids {j*256+tid}
    int srow[4], ssg[4];
#pragma unroll
    for (int j = 0; j < 4; j++) {
        int id  = j * 256 + tid;
        srow[j] = id >> 3;
        ssg[j]  = (id & 7) ^ (srow[j] & 7);
    }

    f32x4 acc[4][4] = {};
    f32x4 xa[4][2];

    // ---- prologue: stage B(0), load+write A(0) ----
#pragma unroll
    for (int j = 0; j < 4; j++)
        stage16(Wt + (n0 + srow[j]) * D + ssg[j] * 8,
                Bls[0] + (size_t)(j * 256 + wave * 64) * 8);
#pragma unroll
    for (int j = 0; j < 4; j++) {
        const float* src = X + (m0 + srow[j]) * D + ssg[j] * 8;
        xa[j][0] = *(const f32x4*)(src);
        xa[j][1] = *(const f32x4*)(src + 4);
    }
#pragma unroll
    for (int j = 0; j < 4; j++) {
        u32x4 w;
        w[0] = cvt_pk_bf16(xa[j][0][0], xa[j][0][1]);
        w[1] = cvt_pk_bf16(xa[j][0][2], xa[j][0][3]);
        w[2] = cvt_pk_bf16(xa[j][1][0], xa[j][1][1]);
        w[3] = cvt_pk_bf16(xa[j][1][2], xa[j][1][3]);
        *(bf16x8*)(Als + (size_t)(j * 256 + tid) * 8) = __builtin_bit_cast(bf16x8, w);
    }
    __syncthreads();

    int c = 0;
    for (int kt = 0; kt < D / 64; kt++) {
        // issue next step's B-stage + A-loads FIRST (latency spans MFMA)
        if (kt + 1 < D / 64) {
            int kn = (kt + 1) * 64;
#pragma unroll
            for (int j = 0; j < 4; j++)
                stage16(Wt + (n0 + srow[j]) * D + kn + ssg[j] * 8,
                        Bls[c ^ 1] + (size_t)(j * 256 + wave * 64) * 8);
#pragma unroll
            for (int j = 0; j < 4; j++) {
                const float* src = X + (m0 + srow[j]) * D + kn + ssg[j] * 8;
                xa[j][0] = *(const f32x4*)(src);
                xa[j][1] = *(const f32x4*)(src + 4);
            }
        }

        // fragments for step kt
        bf16x8 af[2][4], bfr[2][4];
#pragma unroll
        for (int h = 0; h < 2; h++) {
#pragma unroll
            for (int i = 0; i < 4; i++) {
                int rowa = wm + i * 16 + lane15;
                int ga   = (h * 4 + quad) ^ (rowa & 7);
                af[h][i] = *(const bf16x8*)(Als + (size_t)rowa * 64 + ga * 8);
                int rowb = wn + i * 16 + lane15;
                int gb   = (h * 4 + quad) ^ (rowb & 7);
                bfr[h][i] = *(const bf16x8*)(Bls[c] + (size_t)rowb * 64 + gb * 8);
            }
        }
#pragma unroll
        for (int h = 0; h < 2; h++)
#pragma unroll
            for (int mi = 0; mi < 4; mi++)
#pragma unroll
                for (int nf = 0; nf < 4; nf++)
                    acc[mi][nf] = __builtin_amdgcn_mfma_f32_16x16x32_bf16(
                        af[h][mi], bfr[h][nf], acc[mi][nf], 0, 0, 0);

        __syncthreads();   // all waves done reading Als

        if (kt + 1 < D / 64) {
            // write-late: A(kt+1) into the (single) A buffer
#pragma unroll
            for (int j = 0; j < 4; j++) {
                u32x4 w;
                w[0] = cvt_pk_bf16(xa[j][0][0], xa[j][0][1]);
                w[1] = cvt_pk_bf16(xa[j][0][2], xa[j][0][3]);
                w[2] = cvt_pk_bf16(xa[j][1][0], xa[j][1][1]);
                w[3] = cvt_pk_bf16(xa[j][1][2], xa[j][1][3]);
                *(bf16x8*)(Als + (size_t)(j * 256 + tid) * 8) = __builtin_bit_cast(bf16x8, w);
            }
            __syncthreads();  // new Als visible
        }
        c ^= 1;
    }

    const float scl = (which == 0) ? 0.18033688011112042f : 1.0f;
    if (which == 2) {
        // V: pack 4 t-consecutive outputs -> one 8B store
#pragma unroll
        for (int nf = 0; nf < 4; nf++) {
            int n = nblk * 128 + wn + nf * 16 + lane15;
            float bn = bias[n];
            int h = n >> 6, d = n & 63;
#pragma unroll
            for (int mi = 0; mi < 4; mi++) {
                int t0 = mblk * 128 + wm + mi * 16 + quad * 4;
                int b_ = t0 >> 11;
                int tt = t0 & (T - 1);
                u16x4 o;
#pragma unroll
                for (int r = 0; r < 4; r++) o[r] = f2bf(acc[mi][nf][r] + bn);
                *(u16x4*)(Vt + (size_t)((b_ * H + h) * DH + d) * T + tt) = o;
            }
        }
    } else {
        unsigned short* P = (which == 0) ? Qp : Kp;
#pragma unroll
        for (int nf = 0; nf < 4; nf++) {
            int n = nblk * 128 + wn + nf * 16 + lane15;
            float bn = bias[n];
            int h = n >> 6, d = n & 63;
#pragma unroll
            for (int mi = 0; mi < 4; mi++) {
#pragma unroll
                for (int r = 0; r < 4; r++) {
                    int m  = mblk * 128 + wm + mi * 16 + quad * 4 + r;
                    int b_ = m >> 11;
                    int t  = m & (T - 1);
                    P[(size_t)((b_ * H + h) * T + t) * DH + d] =
                        f2bf((acc[mi][nf][r] + bn) * scl);
                }
            }
        }
    }
}

// ---------------------------------------------------------------------------
// Stage 2: flash attention.  This round: 64 q-rows per wave (MI=4; 256 rows
// per block).  The 4 waves of a block read IDENTICAL K/V fragments, and the
// LDS read pipe is the dominant cost (~47 of 88 us) — doubling q-rows per
// wave halves LDS reads, staging, and L2 traffic per unit work.  Grid 512.
// ---------------------------------------------------------------------------
__global__ __launch_bounds__(256, 2) void attn_kernel(
    const unsigned short* __restrict__ Qp,
    const unsigned short* __restrict__ Kp,
    const unsigned short* __restrict__ Vt,
    float* __restrict__ AO) {
    __shared__ __align__(16) unsigned short Kls[2][64 * 64];
    __shared__ __align__(16) unsigned short Vls[2][64 * 64];

    constexpr int NT = T / 64;
    constexpr int MI = 4;   // 16-row q-fragments per wave

    int bx = blockIdx.x;
    // bijective XCD swizzle: grid=512=8*64; XCD x gets bh in [8x, 8x+8)
    int sb = (bx & 7) * 64 + (bx >> 3);
    int qt = sb & 7;            // 8 q-tiles of 256 rows
    int bh = sb >> 3;

    int tid  = threadIdx.x;
    int wave = tid >> 6, lane = tid & 63;
    int lane15 = lane & 15, quad = lane >> 4;

    const unsigned short* Qb = Qp + (size_t)bh * T * DH;
    const unsigned short* Kb = Kp + (size_t)bh * T * DH;
    const unsigned short* Vb = Vt + (size_t)bh * DH * T;

    int qbase = qt * 256 + wave * 64;
    bf16x8 qa[MI][2];
#pragma unroll
    for (int mi = 0; mi < MI; mi++)
#pragma unroll
        for (int hh = 0; hh < 2; hh++)
            qa[mi][hh] = *(const bf16x8*)(
                Qb + (size_t)(qbase + mi * 16 + lane15) * DH + hh * 32 + quad * 8);

    float ps[MI] = {};
    f32x4 O[MI][4] = {};

    // prologue: stage tile 0 into buf 0
#pragma unroll
    for (int i = 0; i < 2; i++) {
        int gl = i * 256 + tid;
        int row = gl >> 3, c = gl & 7;
        int sg = c ^ (row & 7);
        stage16(Kb + (size_t)row * DH + sg * 8,
                &Kls[0][(size_t)(i * 256 + wave * 64) * 8]);
        stage16(Vb + (size_t)row * T + sg * 8,
                &Vls[0][(size_t)(i * 256 + wave * 64) * 8]);
    }
    __syncthreads();

    int cur = 0;
    for (int kt = 0; kt < NT; kt++) {
        if (kt + 1 < NT) {
            int nkb = (kt + 1) * 64;
#pragma unroll
            for (int i = 0; i < 2; i++) {
                int gl = i * 256 + tid;
                int row = gl >> 3, c = gl & 7;
                int sg = c ^ (row & 7);
                stage16(Kb + (size_t)(nkb + row) * DH + sg * 8,
                        &Kls[cur ^ 1][(size_t)(i * 256 + wave * 64) * 8]);
                stage16(Vb + (size_t)row * T + nkb + sg * 8,
                        &Vls[cur ^ 1][(size_t)(i * 256 + wave * 64) * 8]);
            }
        }

        bf16x8 kf[4][2];
#pragma unroll
        for (int nf = 0; nf < 4; nf++) {
            int r = nf * 16 + lane15;
#pragma unroll
            for (int hh = 0; hh < 2; hh++) {
                int ch = (hh * 4 + quad) ^ (r & 7);
                kf[nf][hh] = *(const bf16x8*)(&Kls[cur][(size_t)r * 64 + ch * 8]);
            }
        }

        // S^T = K @ Q^T, then p = exp2(s), pack to bf16 pairs.
        unsigned e[4][MI][2];
        __builtin_amdgcn_s_setprio(1);
#pragma unroll
        for (int nf = 0; nf < 4; nf++) {
#pragma unroll
            for (int mi = 0; mi < MI; mi++) {
                f32x4 st = {};
                st = __builtin_amdgcn_mfma_f32_16x16x32_bf16(
                    kf[nf][0], qa[mi][0], st, 0, 0, 0);
                st = __builtin_amdgcn_mfma_f32_16x16x32_bf16(
                    kf[nf][1], qa[mi][1], st, 0, 0, 0);
                f32x4 p;
#pragma unroll
                for (int r = 0; r < 4; r++) {
                    p[r] = __builtin_amdgcn_exp2f(st[r]);
                    ps[mi] += p[r];
                }
                e[nf][mi][0] = cvt_pk_bf16(p[0], p[1]);
                e[nf][mi][1] = cvt_pk_bf16(p[2], p[3]);
            }
        }
        __builtin_amdgcn_s_setprio(0);

        bf16x8 vf[4][2];
#pragma unroll
        for (int nf = 0; nf < 4; nf++) {
            int r = nf * 16 + lane15;
#pragma unroll
            for (int hh = 0; hh < 2; hh++) {
                int ch = (hh * 4 + quad) ^ (r & 7);
                vf[nf][hh] = *(const bf16x8*)(&Vls[cur][(size_t)r * 64 + ch * 8]);
            }
        }

        __builtin_amdgcn_s_setprio(1);
#pragma unroll
        for (int mi = 0; mi < MI; mi++) {
#pragma unroll
            for (int ks = 0; ks < 2; ks++) {
                unsigned a0 = e[2 * ks][mi][0], b0 = e[2 * ks + 1][mi][0];
                pl32swap(a0, b0);
                pl16swap(a0, b0);
                unsigned a1 = e[2 * ks][mi][1], b1 = e[2 * ks + 1][mi][1];
                pl32swap(a1, b1);
                pl16swap(a1, b1);
                u32x4 w;
                w[0] = a0; w[1] = a1; w[2] = b0; w[3] = b1;
                bf16x8 pa = __builtin_bit_cast(bf16x8, w);
#pragma unroll
                for (int nf = 0; nf < 4; nf++)
                    O[mi][nf] = __builtin_amdgcn_mfma_f32_16x16x32_bf16(
                        pa, vf[nf][ks], O[mi][nf], 0, 0, 0);
            }
        }
        __builtin_amdgcn_s_setprio(0);

        __syncthreads();
        cur ^= 1;
    }

    float dinv[MI][4];
#pragma unroll
    for (int mi = 0; mi < MI; mi++) {
        ps[mi] += __shfl_xor(ps[mi], 16);
        ps[mi] += __shfl_xor(ps[mi], 32);
        float iv = 1.0f / ps[mi];
#pragma unroll
        for (int r = 0; r < 4; r++)
            dinv[mi][r] = __shfl(iv, (lane & 48) + ((lane >> 4) & 3) * 4 + r);
    }

    int hd = bh & 15;
    int b_ = bh >> 4;
#pragma unroll
    for (int mi = 0; mi < MI; mi++) {
#pragma unroll
        for (int r = 0; r < 4; r++) {
            int t = qbase + mi * 16 + quad * 4 + r;
            float* dst = AO + (size_t)(b_ * T + t) * D + hd * DH;
#pragma unroll
            for (int nf = 0; nf < 4; nf++) {
                dst[nf * 16 + lane15] = O[mi][nf][r] * dinv[mi][r];
            }
        }
    }
}

// ---------------------------------------------------------------------------
// Stage 3: residual + LayerNorm, in place on f32 d_out.  f32x4 vectorized.
// ---------------------------------------------------------------------------
__global__ __launch_bounds__(256) void ln_kernel(
    float* io,
    const float* __restrict__ qin,
    const float* __restrict__ gamma,
    const float* __restrict__ beta) {
    int row = blockIdx.x;
    int tid = threadIdx.x;
    size_t base = (size_t)row * D + tid * 4;
    f32x4 xo = *(const f32x4*)(io + base);
    f32x4 xq = *(const f32x4*)(qin + base);
    f32x4 x;
    float sum = 0.f, ss = 0.f;
#pragma unroll
    for (int i = 0; i < 4; i++) {
        x[i] = xo[i] + xq[i];
        sum += x[i];
        ss += x[i] * x[i];
    }
#pragma unroll
    for (int off = 32; off >= 1; off >>= 1) {
        sum += __shfl_xor(sum, off);
        ss  += __shfl_xor(ss, off);
    }
    __shared__ float s1[4], s2[4];
    int wave = tid >> 6, lane = tid & 63;
    if (lane == 0) { s1[wave] = sum; s2[wave] = ss; }
    __syncthreads();
    sum = s1[0] + s1[1] + s1[2] + s1[3];
    ss  = s2[0] + s2[1] + s2[2] + s2[3];
    float mean = sum * (1.0f / D);
    float var  = (ss - sum * mean) * (1.0f / (D - 1));
    var = fmaxf(var, 0.0f);
    float inv = 1.0f / (sqrtf(var) + 1e-8f);
    f32x4 g = *(const f32x4*)(gamma + tid * 4);
    f32x4 bb = *(const f32x4*)(beta + tid * 4);
    f32x4 o;
#pragma unroll
    for (int i = 0; i < 4; i++) o[i] = g[i] * (x[i] - mean) * inv + bb[i];
    *(f32x4*)(io + base) = o;
}

// ---------------------------------------------------------------------------
extern "C" void kernel_launch(void* const* d_in, const int* in_sizes, int n_in,
                              void* d_out, int out_size, void* d_ws, size_t ws_size,
                              hipStream_t stream) {
    (void)in_sizes; (void)n_in; (void)out_size; (void)ws_size;
    const float* xin[3] = {(const float*)d_in[0], (const float*)d_in[1], (const float*)d_in[2]};
    const float* Wq  = (const float*)d_in[3];
    const float* bq  = (const float*)d_in[4];
    const float* Wk  = (const float*)d_in[5];
    const float* bk  = (const float*)d_in[6];
    const float* Wv  = (const float*)d_in[7];
    const float* bv  = (const float*)d_in[8];
    const float* gam = (const float*)d_in[9];
    const float* bet = (const float*)d_in[10];
    float* out = (float*)d_out;

    unsigned short* ws = (unsigned short*)d_ws;
    unsigned short* Qp = ws;
    unsigned short* Kp = Qp + (size_t)BT * D;
    unsigned short* Vt = Kp + (size_t)BT * D;
    unsigned short* WT = (unsigned short*)d_out;   // 3*D*D bf16 (6 MB), dead after gemm

    transpose_w<<<dim3((D / 32) * (D / 32), 3), 256, 0, stream>>>(Wq, Wk, Wv, WT);
    qkv_gemm_fused<<<dim3((BT / 128) * (D / 128), 3), 256, 0, stream>>>(
        xin[0], xin[1], xin[2], WT, bq, bk, bv, Qp, Kp, Vt);
    attn_kernel<<<dim3(B * H * (T / 256)), 256, 0, stream>>>(Qp, Kp, Vt, out);
    ln_kernel<<<dim3(BT), 256, 0, stream>>>(out, xin[0], gam, bet);
}